// Round 10
// baseline (345.375 us; speedup 1.0000x reference)
//
#include <hip/hip_runtime.h>
#include <math.h>

constexpr int N = 50000;
constexpr int E = 800000;
constexpr int D = 32;      // layer dim
constexpr int R = 20;      // relations

// edge kernel geometry: 16 lanes per edge, 2 output cols per lane
constexpr int EG = 2048;                   // blocks
constexpr int ET = 256;                    // threads/block
constexpr int ENG = EG * (ET / 16);        // 32768 16-lane groups
constexpr int ECE = (E + ENG - 1) / ENG;   // 25 sorted edges per group

// node kernel geometry: 4 nodes per 32-lane group
constexpr int NQ = N / 4;                       // 12500 quads
constexpr int NODE_BLKS = (NQ + 7) / 8;         // 1563 blocks (8 groups/block)
constexpr int GES = (E + 255) / 256;            // 3125 scatter/hist blocks

__device__ __forceinline__ unsigned f2bf(float f) {
    unsigned u = __float_as_uint(f);
    return (u + 0x7fffu + ((u >> 16) & 1u)) >> 16;   // RNE to bf16 bits
}
__device__ __forceinline__ float bflo(unsigned u) { return __uint_as_float(u << 16); }
__device__ __forceinline__ float bfhi(unsigned u) { return __uint_as_float(u & 0xffff0000u); }

// ---------------------------------------------------------------------------
// Shared node-quad body: 4 nodes, weights loaded once per quad per k-step.
// Packs per-node records for the 16-lane edge kernel:
//   xbp[n][l] (uint4): cols l and l+16 of xb[0..3] as bf16 pairs
//   sap[n][l] (uint):  sA col l | col l+16
//   dAp[n][l] (uint):  dA col l | col l+16
//   nei[n][j] = self-loop term (fp32 accumulator init)
__device__ __forceinline__ void node_quad(int n0, int j, const float xin[4],
                                          const float* __restrict__ Aw,
                                          const float* __restrict__ bases,
                                          const float* __restrict__ selfw,
                                          uint4* __restrict__ xbp,
                                          unsigned* __restrict__ sap,
                                          unsigned* __restrict__ dAp,
                                          float* __restrict__ nei) {
    float sa[4] = {0,0,0,0}, da[4] = {0,0,0,0}, cu[4] = {0,0,0,0};
    float b0[4] = {0,0,0,0}, b1[4] = {0,0,0,0}, b2[4] = {0,0,0,0}, b3[4] = {0,0,0,0};
#pragma unroll
    for (int i = 0; i < D; ++i) {
        float wsa = Aw[i * D + j];
        float wda = Aw[(D + i) * D + j];
        float w0  = bases[0 * D * D + i * D + j];
        float w1  = bases[1 * D * D + i * D + j];
        float w2  = bases[2 * D * D + i * D + j];
        float w3  = bases[3 * D * D + i * D + j];
        float wcu = selfw[i * D + j];
#pragma unroll
        for (int u = 0; u < 4; ++u) {
            float xi = __shfl(xin[u], i, 32);
            sa[u] = fmaf(xi, wsa, sa[u]);
            da[u] = fmaf(xi, wda, da[u]);
            b0[u] = fmaf(xi, w0, b0[u]);
            b1[u] = fmaf(xi, w1, b1[u]);
            b2[u] = fmaf(xi, w2, b2[u]);
            b3[u] = fmaf(xi, w3, b3[u]);
            cu[u] = fmaf(xi, wcu, cu[u]);
        }
    }
#pragma unroll
    for (int u = 0; u < 4; ++u) {
        int n = n0 + u;
        float sah = __shfl(sa[u], j + 16, 32);
        float dah = __shfl(da[u], j + 16, 32);
        float b0h = __shfl(b0[u], j + 16, 32);
        float b1h = __shfl(b1[u], j + 16, 32);
        float b2h = __shfl(b2[u], j + 16, 32);
        float b3h = __shfl(b3[u], j + 16, 32);
        if (n < N) {
            if (j < 16) {
                uint4 w;
                w.x = f2bf(b0[u]) | (f2bf(b1[u]) << 16);
                w.y = f2bf(b2[u]) | (f2bf(b3[u]) << 16);
                w.z = f2bf(b0h)   | (f2bf(b1h) << 16);
                w.w = f2bf(b2h)   | (f2bf(b3h) << 16);
                xbp[(size_t)n * 16 + j] = w;
                sap[(size_t)n * 16 + j] = f2bf(sa[u]) | (f2bf(sah) << 16);
                dAp[(size_t)n * 16 + j] = f2bf(da[u]) | (f2bf(dah) << 16);
            }
            nei[(size_t)n * D + j] = cu[u];
        }
    }
}

// ---------------------------------------------------------------------------
// hist+rank over edges; trailing blocks compute attnA[2][R][32].
__global__ void hist_rank_attnA(const int* __restrict__ dst,
                                int* __restrict__ cnt,
                                int* __restrict__ rank,
                                const float* __restrict__ attn,
                                const float* __restrict__ Aw0,
                                const float* __restrict__ Ab0,
                                const float* __restrict__ Aw1,
                                const float* __restrict__ Ab1,
                                float* __restrict__ attnA) {
    int b = blockIdx.x;
    if (b < GES) {
        int e = b * 256 + threadIdx.x;
        if (e < E) rank[e] = atomicAdd(&cnt[dst[e]], 1);
    } else {
        int i = (b - GES) * 256 + threadIdx.x;   // 0..1279
        if (i < 2 * R * 32) {
            int l = i / (R * 32), rem = i % (R * 32), r = rem / 32, jj = rem & 31;
            const float* Aw = l ? Aw1 : Aw0;
            const float* Ab = l ? Ab1 : Ab0;
            float acc = Ab[jj];
            for (int k = 0; k < 32; ++k)
                acc = fmaf(attn[r * 32 + k], Aw[(64 + k) * D + jj], acc);
            attnA[i] = acc;
        }
    }
}

// ---------------------------------------------------------------------------
// One-kernel exclusive scan: block b sums cnt[0..b*1024), then scans its chunk.
constexpr int SCB = 1024;
constexpr int NSCB = (N + SCB - 1) / SCB;   // 49

__global__ __launch_bounds__(SCB)
void scan_all(const int* __restrict__ cnt, int* __restrict__ off) {
    __shared__ int sdata[SCB];
    int tid = threadIdx.x;
    int lim = blockIdx.x * SCB;
    int partial = 0;
    for (int i = tid; i < lim; i += SCB) partial += cnt[i];
    sdata[tid] = partial;
    __syncthreads();
    for (int s = SCB / 2; s > 0; s >>= 1) {
        if (tid < s) sdata[tid] += sdata[tid + s];
        __syncthreads();
    }
    int bbase = sdata[0];
    __syncthreads();
    int i = lim + tid;
    int v = (i < N) ? cnt[i] : 0;
    sdata[tid] = v;
    __syncthreads();
    for (int d = 1; d < SCB; d <<= 1) {
        int u = (tid >= d) ? sdata[tid - d] : 0;
        __syncthreads();
        sdata[tid] += u;
        __syncthreads();
    }
    if (i < N) {
        int excl = sdata[tid] - v + bbase;
        off[i] = excl;
        if (i == N - 1) off[N] = excl + v;   // == E
    }
}

// ---------------------------------------------------------------------------
// Fused: blocks [0,GES) scatter edges; blocks [GES,GES+NODE_BLKS) node stage l0.
__global__ __launch_bounds__(256)
void scatter_node_l0(const int* __restrict__ src,
                     const int* __restrict__ dst,
                     const int* __restrict__ ety,
                     const int* __restrict__ off,
                     const int* __restrict__ rank,
                     int2* __restrict__ es,
                     const float* __restrict__ feat,
                     const float* __restrict__ embed,
                     const int* __restrict__ idx,
                     const float* __restrict__ Aw,
                     const float* __restrict__ bases,
                     const float* __restrict__ selfw,
                     uint4* __restrict__ xbp,
                     unsigned* __restrict__ sap,
                     unsigned* __restrict__ dAp,
                     float* __restrict__ nei) {
    int b = blockIdx.x;
    if (b < GES) {
        int e = b * 256 + threadIdx.x;
        if (e < E) {
            int d = dst[e];
            es[off[d] + rank[e]] = make_int2(src[e] | (ety[e] << 16), d);
            if (e == 0) es[E] = make_int2(0, 0);   // pipeline sentinel
        }
        return;
    }
    int qid = ((b - GES) * 256 + threadIdx.x) >> 5;
    if (qid >= NQ) return;
    int j = threadIdx.x & 31;
    int n0 = qid * 4;
    float xin[4];
#pragma unroll
    for (int u = 0; u < 4; ++u) {
        int n = n0 + u;
        xin[u] = (n < N)
            ? ((j < 16) ? feat[n * 16 + j] : embed[idx[n] * 16 + (j - 16)])
            : 0.f;
    }
    node_quad(n0, j, xin, Aw, bases, selfw, xbp, sap, dAp, nei);
}

// ---------------------------------------------------------------------------
// Node stage layer 1: x1 = relu(nei) (fused layer-0 finalize), then quad body.
__global__ __launch_bounds__(256)
void node_stage_l1(const float* __restrict__ Aw,
                   const float* __restrict__ bases,
                   const float* __restrict__ selfw,
                   uint4* __restrict__ xbp,
                   unsigned* __restrict__ sap,
                   unsigned* __restrict__ dAp,
                   float* __restrict__ nei) {
    int qid = (blockIdx.x * 256 + threadIdx.x) >> 5;
    if (qid >= NQ) return;
    int j = threadIdx.x & 31;
    int n0 = qid * 4;
    float xin[4];
#pragma unroll
    for (int u = 0; u < 4; ++u) {
        int n = n0 + u;
        xin[u] = (n < N) ? fmaxf(nei[n * D + j], 0.f) : 0.f;
    }
    node_quad(n0, j, xin, Aw, bases, selfw, xbp, sap, dAp, nei);
}

// ---------------------------------------------------------------------------
// Edge stage: 16 lanes/edge (2 cols/lane), dst-sorted chunk walk, register
// run-accumulation, explicit next-edge software pipeline.
__global__ __launch_bounds__(ET)
void edge_stage(const uint4* __restrict__ xbp,
                const unsigned* __restrict__ sap,
                const unsigned* __restrict__ dAp,
                const float* __restrict__ attnA,
                const float* __restrict__ wcomp,
                const float* __restrict__ Bw,
                const float* __restrict__ Bb,
                const int2* __restrict__ es,
                float* __restrict__ nei) {
    __shared__ float2 attnL[R * 16];
    __shared__ float4 wcL[R];
    int tid = threadIdx.x;
    for (int i = tid; i < R * 16; i += ET) {
        int r = i >> 4, l = i & 15;
        attnL[i] = make_float2(attnA[r * 32 + l], attnA[r * 32 + l + 16]);
    }
    if (tid < R) wcL[tid] = *(const float4*)(wcomp + tid * 4);
    __syncthreads();

    int l = tid & 15;
    int grp = (blockIdx.x * ET + tid) >> 4;
    int k0 = grp * ECE;
    int k1 = k0 + ECE; if (k1 > E) k1 = E;
    if (k0 >= k1) return;

    float bw0 = Bw[l], bw1 = Bw[l + 16], bb = Bb[0];

    // pipeline prologue: edge k0 in flight
    int2 e = es[k0];
    int s = e.x & 0xffff, r = ((unsigned)e.x) >> 16, d = e.y;
    uint4 w   = xbp[(size_t)s * 16 + l];
    unsigned sa2 = sap[(size_t)s * 16 + l];

    int dprev = -1;
    float acc0 = 0.f, acc1 = 0.f, dAv0 = 0.f, dAv1 = 0.f;
    for (int k = k0; k < k1; ++k) {
        // issue next edge's loads early (es[E] sentinel makes k+1 safe)
        int2 en = es[k + 1];
        int sn = en.x & 0xffff, rn = ((unsigned)en.x) >> 16, dn = en.y;
        uint4 wn    = xbp[(size_t)sn * 16 + l];
        unsigned sn2 = sap[(size_t)sn * 16 + l];

        if (d != dprev) {                  // group-uniform branch
            if (dprev >= 0) {
                atomicAdd(&nei[(size_t)dprev * D + l], acc0);
                atomicAdd(&nei[(size_t)dprev * D + l + 16], acc1);
            }
            acc0 = acc1 = 0.f; dprev = d;
            unsigned da2 = dAp[(size_t)d * 16 + l];
            dAv0 = bflo(da2); dAv1 = bfhi(da2);
        }
        float2 at = attnL[r * 16 + l];
        float h0 = fmaxf(bflo(sa2) + dAv0 + at.x, 0.f);
        float h1 = fmaxf(bfhi(sa2) + dAv1 + at.y, 0.f);
        float pp = fmaf(h1, bw1, h0 * bw0);
#pragma unroll
        for (int o = 8; o > 0; o >>= 1) pp += __shfl_xor(pp, o, 16);
        float a = 1.f / (1.f + __expf(-(pp + bb)));
        float4 wc = wcL[r];
        float m0 = wc.x * bflo(w.x);
        m0 = fmaf(wc.y, bfhi(w.x), m0);
        m0 = fmaf(wc.z, bflo(w.y), m0);
        m0 = fmaf(wc.w, bfhi(w.y), m0);
        float m1 = wc.x * bflo(w.z);
        m1 = fmaf(wc.y, bfhi(w.z), m1);
        m1 = fmaf(wc.z, bflo(w.w), m1);
        m1 = fmaf(wc.w, bfhi(w.w), m1);
        acc0 = fmaf(a, m0, acc0);
        acc1 = fmaf(a, m1, acc1);
        // advance pipeline
        e = en; s = sn; r = rn; d = dn; w = wn; sa2 = sn2;
    }
    atomicAdd(&nei[(size_t)dprev * D + l], acc0);
    atomicAdd(&nei[(size_t)dprev * D + l + 16], acc1);
}

// ---------------------------------------------------------------------------
// out = relu(nei)
__global__ void finalize(const float4* __restrict__ nei, float4* __restrict__ out) {
    int t = blockIdx.x * blockDim.x + threadIdx.x;
    if (t >= N * D / 4) return;
    float4 v = nei[t];
    v.x = fmaxf(v.x, 0.f); v.y = fmaxf(v.y, 0.f);
    v.z = fmaxf(v.z, 0.f); v.w = fmaxf(v.w, 0.f);
    out[t] = v;
}

// ---------------------------------------------------------------------------
extern "C" void kernel_launch(void* const* d_in, const int* in_sizes, int n_in,
                              void* d_out, int out_size, void* d_ws, size_t ws_size,
                              hipStream_t stream) {
    const float* feat  = (const float*)d_in[0];
    const float* embed = (const float*)d_in[1];
    const float* attn  = (const float*)d_in[2];
    const int*   idx   = (const int*)d_in[3];
    const int*   src   = (const int*)d_in[4];
    const int*   dst   = (const int*)d_in[5];
    const int*   ety   = (const int*)d_in[6];
    const float* bases[2] = {(const float*)d_in[7],  (const float*)d_in[14]};
    const float* wcomp[2] = {(const float*)d_in[8],  (const float*)d_in[15]};
    const float* selfw[2] = {(const float*)d_in[9],  (const float*)d_in[16]};
    const float* Aw[2]    = {(const float*)d_in[10], (const float*)d_in[17]};
    const float* Ab[2]    = {(const float*)d_in[11], (const float*)d_in[18]};
    const float* Bw[2]    = {(const float*)d_in[12], (const float*)d_in[19]};
    const float* Bb[2]    = {(const float*)d_in[13], (const float*)d_in[20]};
    float* out = (float*)d_out;

    // --- workspace layout ---
    char* wsb = (char*)d_ws;
    size_t o = 0;
    uint4* xbp     = (uint4*)(wsb + o);    o += (size_t)N * 16 * 16;      // 12.8 MB
    unsigned* sap  = (unsigned*)(wsb + o); o += (size_t)N * 16 * 4;       // 3.2 MB
    unsigned* dAp  = (unsigned*)(wsb + o); o += (size_t)N * 16 * 4;       // 3.2 MB
    float* nei     = (float*)(wsb + o);    o += (size_t)N * D * 4;        // 6.4 MB
    float* attnA   = (float*)(wsb + o);    o += (size_t)2 * R * D * 4;
    o = (o + 7) & ~(size_t)7;
    int2* es       = (int2*)(wsb + o);     o += (size_t)(E + 1) * 8;      // 6.4 MB
    int* cnt       = (int*)(wsb + o);      o += (size_t)N * 4;
    int* off       = (int*)(wsb + o);      o += (size_t)(N + 2) * 4;
    int* rank      = (int*)(wsb + o);      o += (size_t)E * 4;            // 3.2 MB

    dim3 blk(256);
    int gf = (N * D / 4 + 255) / 256;

    // sort + tiny precompute
    hipMemsetAsync(cnt, 0, (size_t)N * 4, stream);
    hist_rank_attnA<<<GES + 5, blk, 0, stream>>>(dst, cnt, rank, attn,
                                                 Aw[0], Ab[0], Aw[1], Ab[1], attnA);
    scan_all<<<NSCB, SCB, 0, stream>>>(cnt, off);

    // fused scatter + layer-0 node stage
    scatter_node_l0<<<GES + NODE_BLKS, blk, 0, stream>>>(
        src, dst, ety, off, rank, es,
        feat, embed, idx, Aw[0], bases[0], selfw[0], xbp, sap, dAp, nei);
    edge_stage<<<EG, ET, 0, stream>>>(xbp, sap, dAp, attnA, wcomp[0],
                                      Bw[0], Bb[0], es, nei);
    // layer 1
    node_stage_l1<<<NODE_BLKS, blk, 0, stream>>>(Aw[1], bases[1], selfw[1],
                                                 xbp, sap, dAp, nei);
    edge_stage<<<EG, ET, 0, stream>>>(xbp, sap, dAp, attnA + (size_t)R * D,
                                      wcomp[1], Bw[1], Bb[1], es, nei);
    finalize<<<gf, blk, 0, stream>>>((const float4*)nei, (float4*)out);
}